// Round 1
// 505.083 us; speedup vs baseline: 1.0176x; 1.0176x over previous
//
#include <hip/hip_runtime.h>
#include <stdint.h>

typedef __bf16 bf16x8 __attribute__((ext_vector_type(8)));
typedef float f32x4 __attribute__((ext_vector_type(4)));

// ---------------------------------------------------------------------------
// Fused prep: (a) f32->bf16 convert of the 4 weight matrices, (b) time-shift
// mix producing all three mixed A-matrices (bf16). Block-uniform branch.
// ---------------------------------------------------------------------------
__global__ void prep_kernel(const float* __restrict__ w0, const float* __restrict__ w1,
                            const float* __restrict__ w2, const float* __restrict__ w3,
                            __bf16* __restrict__ o0, __bf16* __restrict__ o1,
                            __bf16* __restrict__ o2, __bf16* __restrict__ o3,
                            long DD, unsigned cvtBlocks,
                            const float* __restrict__ x,
                            const float* __restrict__ mk, const float* __restrict__ mv,
                            const float* __restrict__ mr,
                            __bf16* __restrict__ ok, __bf16* __restrict__ ov,
                            __bf16* __restrict__ orr,
                            int T, int D, long total) {
    if (blockIdx.x < cvtBlocks) {
        long idx = ((long)blockIdx.x * blockDim.x + threadIdx.x) * 8;
        if (idx >= 4 * DD) return;
        int w = (int)(idx / DD);            // block-uniform (DD % 2048 == 0)
        long off = idx - (long)w * DD;
        const float* in = (w == 0) ? w0 : (w == 1) ? w1 : (w == 2) ? w2 : w3;
        __bf16* out     = (w == 0) ? o0 : (w == 1) ? o1 : (w == 2) ? o2 : o3;
        f32x4 a = *(const f32x4*)(in + off);
        f32x4 b = *(const f32x4*)(in + off + 4);
        bf16x8 o;
#pragma unroll
        for (int i = 0; i < 4; ++i) { o[i] = (__bf16)a[i]; o[i + 4] = (__bf16)b[i]; }
        *(bf16x8*)(out + off) = o;
    } else {
        long idx = ((long)(blockIdx.x - cvtBlocks) * blockDim.x + threadIdx.x) * 8;
        if (idx >= total) return;
        int d = (int)(idx % D);
        long bt = idx / D;
        int t = (int)(bt % T);

        f32x4 x0 = *(const f32x4*)(x + idx);
        f32x4 x1 = *(const f32x4*)(x + idx + 4);
        f32x4 l0 = {}, l1 = {};
        if (t != 0) {
            l0 = *(const f32x4*)(x + idx - D);
            l1 = *(const f32x4*)(x + idx - D + 4);
        }
        const float* mw[3] = {mk, mv, mr};
        __bf16* ow[3] = {ok, ov, orr};
#pragma unroll
        for (int s = 0; s < 3; ++s) {
            f32x4 m0 = *(const f32x4*)(mw[s] + d);
            f32x4 m1 = *(const f32x4*)(mw[s] + d + 4);
            bf16x8 o;
#pragma unroll
            for (int i = 0; i < 4; ++i) {
                o[i]     = (__bf16)(x0[i] * m0[i] + l0[i] * (1.0f - m0[i]));
                o[i + 4] = (__bf16)(x1[i] * m1[i] + l1[i] * (1.0f - m1[i]));
            }
            *(bf16x8*)(ow[s] + idx) = o;
        }
    }
}

// ---------------------------------------------------------------------------
// 256x256 8-phase GEMM body (m201/T2+T3+T4+T5 structure).
// 512 threads = 8 waves (2M x 4N); per-wave output 128x64; BK=64.
// LDS 128 KiB: double-buffered [256][64] bf16 A and B tiles, XOR-chunk
// swizzled (chunk ^= row&7) -> ds_read_b128 conflict-free (measured 0 on the
// identical swizzle at 128^2 scale).
// K-loop: 4 quadrant-phases per K-tile, counted vmcnt(8) once per tile at
// phase 3 -- the staged next-next-tile loads stay in flight across 4 phases.
// ---------------------------------------------------------------------------
template <typename CT>
__device__ __attribute__((always_inline))
void gemm256_body(const __bf16* __restrict__ A, const __bf16* __restrict__ Bt,
                  CT* __restrict__ C, int M, int N, int K) {
    __shared__ __align__(16) __bf16 sA[2][256 * 64];
    __shared__ __align__(16) __bf16 sB[2][256 * 64];

    const int tid  = threadIdx.x;
    const int lane = tid & 63;
    const int wave = tid >> 6;
    const int wm = wave >> 2;          // 0..1  (M half)
    const int wn = wave & 3;           // 0..3  (N quarter)

    // XCD-aware bijective swizzle (nwg = 256, %8 == 0)
    int id  = blockIdx.y * gridDim.x + blockIdx.x;
    int nwg = gridDim.x * gridDim.y;
    int wg  = (id & 7) * (nwg >> 3) + (id >> 3);
    int bx  = wg % gridDim.x;
    int by  = wg / gridDim.x;
    const int m0 = by * 256;
    const int n0 = bx * 256;

    // staging: per thread 4 A-loads + 4 B-loads of 16B per K-tile.
    // load l covers rows l*64 + (tid>>3); LDS dest is linear (tid*16B within
    // each 8KB stripe); global source column pre-swizzled (chunk ^ row&7).
    const int rsub = tid >> 3;                            // 0..63
    const int swzc = ((tid & 7) ^ (rsub & 7)) << 3;       // source col (elems)
    const __bf16* gA = A  + (long)(m0 + rsub) * K + swzc;
    const __bf16* gB = Bt + (long)(n0 + rsub) * K + swzc;

    const int NT = K >> 6;             // 64-wide K-tiles

    auto stage = [&](int buf, int t) {
        const long ko = (long)t * 64;
        __bf16* la = &sA[buf][wave * 512];   // wave-uniform base (1KB/wave)
        __bf16* lb = &sB[buf][wave * 512];
#pragma unroll
        for (int l = 0; l < 4; ++l) {
            __builtin_amdgcn_global_load_lds(
                (const __attribute__((address_space(1))) void*)(gA + (long)l * 64 * K + ko),
                (__attribute__((address_space(3))) void*)(la + l * 4096), 16, 0, 0);
            __builtin_amdgcn_global_load_lds(
                (const __attribute__((address_space(1))) void*)(gB + (long)l * 64 * K + ko),
                (__attribute__((address_space(3))) void*)(lb + l * 4096), 16, 0, 0);
        }
    };

    const int q  = lane >> 4;
    const int ml = lane & 15;
    const int m7 = ml & 7;

    f32x4 acc[8][4] = {};
    bf16x8 af[4][2];   // current mg's 4 M-frags x 2 k-slices
    bf16x8 bf[4][2];   // all 4 N-frags x 2 k-slices (resident whole tile)

    // prologue: stage tiles 0 and 1, wait for tile 0 (tile 1 stays in flight)
    stage(0, 0);
    stage(1, 1);
    asm volatile("s_waitcnt vmcnt(8)" ::: "memory");
    __builtin_amdgcn_s_barrier();

    for (int t = 0; t < NT; ++t) {
        const int cur = t & 1;
        const __bf16* pa = &sA[cur][wm * 128 * 64];
        const __bf16* pb = &sB[cur][wn * 64 * 64];

        // ---- phase 0: quadrant (mg=0, j=0..1); 12 ds_reads ----
#pragma unroll
        for (int f = 0; f < 4; ++f)
#pragma unroll
            for (int ks = 0; ks < 2; ++ks)
                af[f][ks] = *(const bf16x8*)(pa + (f * 16 + ml) * 64 + ((ks * 4 + q) ^ m7) * 8);
#pragma unroll
        for (int j = 0; j < 2; ++j)
#pragma unroll
            for (int ks = 0; ks < 2; ++ks)
                bf[j][ks] = *(const bf16x8*)(pb + (j * 16 + ml) * 64 + ((ks * 4 + q) ^ m7) * 8);
        __builtin_amdgcn_s_barrier();
        asm volatile("s_waitcnt lgkmcnt(0)" ::: "memory");
        __builtin_amdgcn_s_setprio(1);
#pragma unroll
        for (int f = 0; f < 4; ++f)
#pragma unroll
            for (int j = 0; j < 2; ++j)
#pragma unroll
                for (int ks = 0; ks < 2; ++ks)
                    acc[f][j] = __builtin_amdgcn_mfma_f32_16x16x32_bf16(
                        af[f][ks], bf[j][ks], acc[f][j], 0, 0, 0);
        __builtin_amdgcn_s_setprio(0);
        __builtin_amdgcn_s_barrier();

        // ---- phase 1: quadrant (mg=0, j=2..3); 4 ds_reads ----
#pragma unroll
        for (int j = 2; j < 4; ++j)
#pragma unroll
            for (int ks = 0; ks < 2; ++ks)
                bf[j][ks] = *(const bf16x8*)(pb + (j * 16 + ml) * 64 + ((ks * 4 + q) ^ m7) * 8);
        __builtin_amdgcn_s_barrier();
        asm volatile("s_waitcnt lgkmcnt(0)" ::: "memory");
        __builtin_amdgcn_s_setprio(1);
#pragma unroll
        for (int f = 0; f < 4; ++f)
#pragma unroll
            for (int j = 2; j < 4; ++j)
#pragma unroll
                for (int ks = 0; ks < 2; ++ks)
                    acc[f][j] = __builtin_amdgcn_mfma_f32_16x16x32_bf16(
                        af[f][ks], bf[j][ks], acc[f][j], 0, 0, 0);
        __builtin_amdgcn_s_setprio(0);
        __builtin_amdgcn_s_barrier();

        // ---- phase 2: quadrant (mg=1, j=2..3); 8 ds_reads ----
#pragma unroll
        for (int f = 0; f < 4; ++f)
#pragma unroll
            for (int ks = 0; ks < 2; ++ks)
                af[f][ks] = *(const bf16x8*)(pa + (64 + f * 16 + ml) * 64 + ((ks * 4 + q) ^ m7) * 8);
        __builtin_amdgcn_s_barrier();
        asm volatile("s_waitcnt lgkmcnt(0)" ::: "memory");
        __builtin_amdgcn_s_setprio(1);
#pragma unroll
        for (int f = 0; f < 4; ++f)
#pragma unroll
            for (int j = 2; j < 4; ++j)
#pragma unroll
                for (int ks = 0; ks < 2; ++ks)
                    acc[4 + f][j] = __builtin_amdgcn_mfma_f32_16x16x32_bf16(
                        af[f][ks], bf[j][ks], acc[4 + f][j], 0, 0, 0);
        __builtin_amdgcn_s_setprio(0);
        __builtin_amdgcn_s_barrier();
        // all reads of buf[cur] are complete chip-wide past this barrier.

        // ---- phase 3: quadrant (mg=1, j=0..1); no reads.
        //      Stage tile t+2 into buf[cur] (free now); counted vmcnt(8)
        //      certifies tile t+1 while t+2's 8 loads stay in flight. ----
        if (t + 2 < NT) stage(cur, t + 2);
        __builtin_amdgcn_s_setprio(1);
#pragma unroll
        for (int f = 0; f < 4; ++f)
#pragma unroll
            for (int j = 0; j < 2; ++j)
#pragma unroll
                for (int ks = 0; ks < 2; ++ks)
                    acc[4 + f][j] = __builtin_amdgcn_mfma_f32_16x16x32_bf16(
                        af[f][ks], bf[j][ks], acc[4 + f][j], 0, 0, 0);
        __builtin_amdgcn_s_setprio(0);
        if (t + 2 < NT) {
            asm volatile("s_waitcnt vmcnt(8)" ::: "memory");
        } else if (t + 1 < NT) {
            asm volatile("s_waitcnt vmcnt(0)" ::: "memory");
        }
        if (t + 1 < NT) __builtin_amdgcn_s_barrier();
    }

    // epilogue
    const long cm = (long)m0 + wm * 128;
    const int  cn = n0 + wn * 64;
#pragma unroll
    for (int i = 0; i < 8; ++i) {
        const int row = (i >> 2) * 64 + (i & 3) * 16 + q * 4;
#pragma unroll
        for (int j = 0; j < 4; ++j) {
            const int col = cn + j * 16 + ml;
#pragma unroll
            for (int rg = 0; rg < 4; ++rg)
                C[(cm + row + rg) * (long)N + col] = (CT)acc[i][j][rg];
        }
    }
}

template <typename CT>
__global__ __launch_bounds__(512, 2)
void gemm_bt(const __bf16* __restrict__ A, const __bf16* __restrict__ Bt,
             CT* __restrict__ C, int M, int N, int K) {
    gemm256_body<CT>(A, Bt, C, M, N, K);
}

// z-batched pair (v and r GEMMs), both bf16 outputs.
__global__ __launch_bounds__(512, 2)
void gemm_bt2(const __bf16* __restrict__ A0, const __bf16* __restrict__ A1,
              const __bf16* __restrict__ B0, const __bf16* __restrict__ B1,
              __bf16* __restrict__ C0, __bf16* __restrict__ C1,
              int M, int N, int K) {
    if (blockIdx.z == 0) gemm256_body<__bf16>(A0, B0, C0, M, N, K);
    else                 gemm256_body<__bf16>(A1, B1, C1, M, N, K);
}

// ---------------------------------------------------------------------------
// Chunk-parallel WKV scan (verified round 3). k f32, v/r bf16.
// ---------------------------------------------------------------------------
__global__ void wkv_pass1(const float* __restrict__ kk, const __bf16* __restrict__ vv,
                          const float* __restrict__ td,
                          float* __restrict__ al, float* __restrict__ bl,
                          float* __restrict__ el,
                          int Bn, int T, int D, int C, int L) {
    int gid = blockIdx.x * blockDim.x + threadIdx.x;
    int BD = Bn * D;
    if (gid >= BD * C) return;
    int c  = gid / BD;
    int bd = gid - c * BD;
    int b  = bd / D;
    int d  = bd - b * D;

    float w = __expf(td[d]);
    float alpha = 0.f, beta = 0.f, eps = -1e30f;
    long base = ((long)b * T + (long)c * L) * D + d;

    const int P = 8;
    float kb0[P], vb0[P], kb1[P], vb1[P];

    auto step = [&](float kt, float vt) {
        float ww2  = eps - w;
        float tau2 = fmaxf(ww2, kt);
        float e1b  = __expf(ww2 - tau2);
        float e2b  = __expf(kt - tau2);
        alpha = e1b * alpha + e2b * vt;
        beta  = e1b * beta + e2b;
        eps   = tau2;
    };

#pragma unroll
    for (int j = 0; j < P; ++j) {
        long o = base + (long)j * D;
        kb0[j] = kk[o]; vb0[j] = (float)vv[o];
    }
    for (int t0 = 0; t0 < L; t0 += 2 * P) {
#pragma unroll
        for (int j = 0; j < P; ++j) {
            long o = base + (long)(t0 + P + j) * D;
            kb1[j] = kk[o]; vb1[j] = (float)vv[o];
        }
#pragma unroll
        for (int j = 0; j < P; ++j) step(kb0[j], vb0[j]);
        if (t0 + 2 * P < L) {
#pragma unroll
            for (int j = 0; j < P; ++j) {
                long o = base + (long)(t0 + 2 * P + j) * D;
                kb0[j] = kk[o]; vb0[j] = (float)vv[o];
            }
        }
#pragma unroll
        for (int j = 0; j < P; ++j) step(kb1[j], vb1[j]);
    }
    al[gid] = alpha; bl[gid] = beta; el[gid] = eps;
}

__global__ void wkv_pass2(const float* __restrict__ kk, const __bf16* __restrict__ vv,
                          const __bf16* __restrict__ rr,
                          const float* __restrict__ td, const float* __restrict__ tf,
                          const float* __restrict__ al, const float* __restrict__ bl,
                          const float* __restrict__ el,
                          __bf16* __restrict__ out,
                          int Bn, int T, int D, int C, int L) {
    int gid = blockIdx.x * blockDim.x + threadIdx.x;
    int BD = Bn * D;
    if (gid >= BD * C) return;
    int c  = gid / BD;      // block-uniform (BD % 256 == 0)
    int bd = gid - c * BD;
    int b  = bd / D;
    int d  = bd - b * D;

    float u = tf[d];
    float w = __expf(td[d]);

    // --- fused combine: fold chunks 0..c-1 into this chunk's inbound state ---
    float alpha = 0.f, beta = 0.f, eps = -1e30f;
    {
        float wL = w * (float)L;
        for (int cc = 0; cc < c; ++cc) {
            int idx = cc * BD + bd;
            float ed  = eps - wL;
            float la = al[idx], lb = bl[idx], le = el[idx];
            float tau = fmaxf(ed, le);
            float e1  = __expf(ed - tau);
            float e2  = __expf(le - tau);
            alpha = alpha * e1 + la * e2;
            beta  = beta * e1 + lb * e2;
            eps   = tau;
        }
    }

    long base = ((long)b * T + (long)c * L) * D + d;

    const int P = 8;
    float kb0[P], vb0[P], rb0[P], kb1[P], vb1[P], rb1[P];

    auto step = [&](float kt, float vt, float rt, int tIdx) {
        float ww  = u + kt;
        float tau = fmaxf(eps, ww);
        float e1  = __expf(eps - tau);
        float e2  = __expf(ww - tau);
        float num = e1 * alpha + e2 * vt;
        float den = e1 * beta + e2;
        float o_  = num * __builtin_amdgcn_rcpf(den);
        float ww2  = eps - w;
        float tau2 = fmaxf(ww2, kt);
        float e1b  = __expf(ww2 - tau2);
        float e2b  = __expf(kt - tau2);
        alpha = e1b * alpha + e2b * vt;
        beta  = e1b * beta + e2b;
        eps   = tau2;
        float sr = __builtin_amdgcn_rcpf(1.0f + __expf(-rt));
        out[base + (long)tIdx * D] = (__bf16)(o_ * sr);
    };

#pragma unroll
    for (int j = 0; j < P; ++j) {
        long o = base + (long)j * D;
        kb0[j] = kk[o]; vb0[j] = (float)vv[o]; rb0[j] = (float)rr[o];
    }
    for (int t0 = 0; t0 < L; t0 += 2 * P) {
#pragma unroll
        for (int j = 0; j < P; ++j) {
            long o = base + (long)(t0 + P + j) * D;
            kb1[j] = kk[o]; vb1[j] = (float)vv[o]; rb1[j] = (float)rr[o];
        }
#pragma unroll
        for (int j = 0; j < P; ++j) step(kb0[j], vb0[j], rb0[j], t0 + j);
        if (t0 + 2 * P < L) {
#pragma unroll
            for (int j = 0; j < P; ++j) {
                long o = base + (long)(t0 + 2 * P + j) * D;
                kb0[j] = kk[o]; vb0[j] = (float)vv[o]; rb0[j] = (float)rr[o];
            }
        }
#pragma unroll
        for (int j = 0; j < P; ++j) step(kb1[j], vb1[j], rb1[j], t0 + P + j);
    }
}

// ---------------------------------------------------------------------------
extern "C" void kernel_launch(void* const* d_in, const int* in_sizes, int n_in,
                              void* d_out, int out_size, void* d_ws, size_t ws_size,
                              hipStream_t stream) {
    const float* x  = (const float*)d_in[0];
    const float* td = (const float*)d_in[1];
    const float* tf = (const float*)d_in[2];
    const float* mk = (const float*)d_in[3];
    const float* mv = (const float*)d_in[4];
    const float* mr = (const float*)d_in[5];
    const float* Wk = (const float*)d_in[6];
    const float* Wv = (const float*)d_in[7];
    const float* Wr = (const float*)d_in[8];
    const float* Wo = (const float*)d_in[9];
    float* out = (float*)d_out;

    const int D = in_sizes[1];                    // 2048
    const int T = 2048;
    const long total = (long)in_sizes[0];         // B*T*D
    const int Bn = (int)(total / ((long)T * D));  // 4
    const int M = Bn * T;
    const long DD = (long)D * D;
    const int C = 32;                             // scan chunks
    const int L = T / C;                          // 64
    const int BD = Bn * D;
    const int S = BD * C;

    // --- workspace layout (peak 192 MB; aliasing relies on stream order) ---
    char* p = (char*)d_ws;
    __bf16* xmk = (__bf16*)p;            p += total * 2;   // dead after gemm_k
    __bf16* xmv = (__bf16*)p;            p += total * 2;   // dead after gemm_bt2
    __bf16* xmr = (__bf16*)p;            p += total * 2;   // dead after gemm_bt2
    __bf16* wkb = (__bf16*)p;            p += DD * 2;      // dead after gemm_k
    __bf16* wvb = (__bf16*)p;            p += DD * 2;      // dead after gemm_bt2
    __bf16* wrb = (__bf16*)p;            p += DD * 2;      // dead after gemm_bt2
    __bf16* wob = (__bf16*)p;            p += DD * 2;      // live till end
    __bf16* vb  = (__bf16*)p;            p += total * 2;
    __bf16* rb  = (__bf16*)p;            p += total * 2;

    float*  kf = (float*)xmv;            // 64 MB over dead xmv+xmr
    __bf16* xo = xmk;                    // pass2 output over dead xmk
    float*  st = (float*)wkb;            // 3.1 MB scan state over dead wkb
    float *al = st, *bl = st + S, *el = st + 2 * S;

    unsigned cvtBlocks = (unsigned)((4 * DD / 8 + 255) / 256);
    unsigned mixBlocks = (unsigned)((total / 8 + 255) / 256);
    dim3 prepGrid(cvtBlocks + mixBlocks);
    dim3 gemmGrid(D / 256, M / 256);              // (8, 32)
    dim3 gemm2Grid(D / 256, M / 256, 2);
    dim3 p12Grid((S + 255) / 256);

    prep_kernel<<<prepGrid, 256, 0, stream>>>(Wk, Wv, Wr, Wo, wkb, wvb, wrb, wob,
                                              DD, cvtBlocks,
                                              x, mk, mv, mr, xmk, xmv, xmr,
                                              T, D, total);

    // v and r GEMMs first (they consume xmv/xmr, freeing the space kf reuses)
    gemm_bt2<<<gemm2Grid, 512, 0, stream>>>(xmv, xmr, wvb, wrb, vb, rb, M, D, D);
    gemm_bt<float><<<gemmGrid, 512, 0, stream>>>(xmk, wkb, kf, M, D, D);

    wkv_pass1<<<p12Grid, 256, 0, stream>>>(kf, vb, td, al, bl, el, Bn, T, D, C, L);
    wkv_pass2<<<p12Grid, 256, 0, stream>>>(kf, vb, rb, td, tf, al, bl, el, xo,
                                           Bn, T, D, C, L);

    gemm_bt<float><<<gemmGrid, 512, 0, stream>>>(xo, wob, out, M, D, D);
}